// Round 3
// baseline (16174.510 us; speedup 1.0000x reference)
//
#include <hip/hip_runtime.h>
#include <math.h>

#define N_ROWS   16384
#define DIM      512
#define DQV      128          // DIM/4 float4s per row
#define K_CODES  8192
#define BM       64           // rows per block
#define BK       512          // codes per strip
#define BD       8            // d-chunk per tile
#define DCS      (DIM / BD)   // 64 d-chunks
#define NSTRIP   (K_CODES / BK)
#define THREADS  256

#define OUT_LOSS 8388608
#define OUT_PERP 8388609
#define OUT_IDX  8388610

__global__ void init_ws(double* ws_loss, int* ws_maxidx) {
    *ws_loss = 0.0;
    *ws_maxidx = 0;
}

// ---- numpy pairwise-sum emulation of xx[n] = np.sum(flat**2, axis=1) ----
__device__ __forceinline__ float p128_sq(const float4* p) {
    float4 q0 = p[0], q1 = p[1];
    float r0 = __fmul_rn(q0.x, q0.x), r1 = __fmul_rn(q0.y, q0.y);
    float r2 = __fmul_rn(q0.z, q0.z), r3 = __fmul_rn(q0.w, q0.w);
    float r4 = __fmul_rn(q1.x, q1.x), r5 = __fmul_rn(q1.y, q1.y);
    float r6 = __fmul_rn(q1.z, q1.z), r7 = __fmul_rn(q1.w, q1.w);
    #pragma unroll
    for (int t = 1; t < 16; ++t) {
        q0 = p[2 * t]; q1 = p[2 * t + 1];
        r0 = __fadd_rn(r0, __fmul_rn(q0.x, q0.x));
        r1 = __fadd_rn(r1, __fmul_rn(q0.y, q0.y));
        r2 = __fadd_rn(r2, __fmul_rn(q0.z, q0.z));
        r3 = __fadd_rn(r3, __fmul_rn(q0.w, q0.w));
        r4 = __fadd_rn(r4, __fmul_rn(q1.x, q1.x));
        r5 = __fadd_rn(r5, __fmul_rn(q1.y, q1.y));
        r6 = __fadd_rn(r6, __fmul_rn(q1.z, q1.z));
        r7 = __fadd_rn(r7, __fmul_rn(q1.w, q1.w));
    }
    return __fadd_rn(__fadd_rn(__fadd_rn(r0, r1), __fadd_rn(r2, r3)),
                     __fadd_rn(__fadd_rn(r4, r5), __fadd_rn(r6, r7)));
}

__global__ __launch_bounds__(256) void xx_kernel(const float4* __restrict__ x4,
                                                 float* __restrict__ xx) {
    int row = blockIdx.x * 256 + threadIdx.x;
    const float4* p = x4 + (size_t)row * DQV;
    float a = p128_sq(p);
    float b = p128_sq(p + 32);
    float c = p128_sq(p + 64);
    float d = p128_sq(p + 96);
    xx[row] = __fadd_rn(__fadd_rn(a, b), __fadd_rn(c, d));
}

__global__ __launch_bounds__(THREADS, 2) void vq_main(const float* __restrict__ x,
                                                      const float* __restrict__ emb,
                                                      const float* __restrict__ xx,
                                                      float* __restrict__ out,
                                                      double* __restrict__ ws_loss,
                                                      int* __restrict__ ws_maxidx) {
    // LDS: 2*16KB (Et) + 2*2KB (Xt) + 256B = ~37 KB  -> 2 blocks/CU
    __shared__ float Et[2][BD * BK];   // E tile [dd][code], double-buffered
    __shared__ float Xt[2][BD * BM];   // X tile [dd][row], double-buffered
    __shared__ int   idxRow[BM];

    const int tid = threadIdx.x;
    const int tx  = tid & 31;             // code group
    const int ty  = tid >> 5;             // row group 0..7
    const int r0  = blockIdx.x * BM;

    const float4* x4   = (const float4*)x;
    const float4* emb4 = (const float4*)emb;
    float4*       out4 = (float4*)out;

    const int c0 = tid;        // staging code ids within strip
    const int c1 = tid + 256;
    const int xr   = tid >> 1;            // staging row (tid<128)
    const int xpart= tid & 1;             // which float4 of the d-chunk

    // per-thread row norms (ref: s = fl(xx - 2*dot); ee vanishes in fp32 ulp(xx))
    float xrow[8];
    #pragma unroll
    for (int i = 0; i < 8; ++i) xrow[i] = xx[r0 + 8 * ty + i];

    float bestv[8];
    int   besti[8];
    #pragma unroll
    for (int i = 0; i < 8; ++i) { bestv[i] = 3.402823466e38f; besti[i] = 0; }

    float4 pe0, pe1, pe2, pe3, px;

    // prefetch (strip 0, dc 0)
    {
        pe0 = emb4[(size_t)c0 * DQV + 0];
        pe1 = emb4[(size_t)c0 * DQV + 1];
        pe2 = emb4[(size_t)c1 * DQV + 0];
        pe3 = emb4[(size_t)c1 * DQV + 1];
        if (tid < 128) px = x4[(size_t)(r0 + xr) * DQV + xpart];
    }

    for (int kc = 0; kc < NSTRIP; ++kc) {
        const int k0 = kc * BK;

        float acc[8][16];
        #pragma unroll
        for (int i = 0; i < 8; ++i)
            #pragma unroll
            for (int j = 0; j < 16; ++j) acc[i][j] = 0.0f;

        __syncthreads();   // prior strip finished all reads of buf0
        // store prefetched (kc, dc=0) tile into buf0
        {
            Et[0][0 * BK + c0] = pe0.x; Et[0][1 * BK + c0] = pe0.y;
            Et[0][2 * BK + c0] = pe0.z; Et[0][3 * BK + c0] = pe0.w;
            Et[0][4 * BK + c0] = pe1.x; Et[0][5 * BK + c0] = pe1.y;
            Et[0][6 * BK + c0] = pe1.z; Et[0][7 * BK + c0] = pe1.w;
            Et[0][0 * BK + c1] = pe2.x; Et[0][1 * BK + c1] = pe2.y;
            Et[0][2 * BK + c1] = pe2.z; Et[0][3 * BK + c1] = pe2.w;
            Et[0][4 * BK + c1] = pe3.x; Et[0][5 * BK + c1] = pe3.y;
            Et[0][6 * BK + c1] = pe3.z; Et[0][7 * BK + c1] = pe3.w;
            if (tid < 128) {
                int db = 4 * xpart;
                Xt[0][(db + 0) * BM + xr] = px.x;
                Xt[0][(db + 1) * BM + xr] = px.y;
                Xt[0][(db + 2) * BM + xr] = px.z;
                Xt[0][(db + 3) * BM + xr] = px.w;
            }
        }

        for (int dc = 0; dc < DCS; ++dc) {
            const int buf = dc & 1;
            __syncthreads();   // buf ready; other buf's readers done

            // prefetch next tile (next dc, or next strip's dc=0)
            {
                int nk0, ndq;
                if (dc < DCS - 1) { nk0 = k0; ndq = 2 * (dc + 1); }
                else              { nk0 = (kc < NSTRIP - 1) ? k0 + BK : 0; ndq = 0; }
                pe0 = emb4[(size_t)(nk0 + c0) * DQV + ndq];
                pe1 = emb4[(size_t)(nk0 + c0) * DQV + ndq + 1];
                pe2 = emb4[(size_t)(nk0 + c1) * DQV + ndq];
                pe3 = emb4[(size_t)(nk0 + c1) * DQV + ndq + 1];
                if (tid < 128) px = x4[(size_t)(r0 + xr) * DQV + ndq + xpart];
            }

            // k-sequential fp32 FMA chain per (row,code) — bit-matches BLAS GEBP
            #pragma unroll
            for (int dd = 0; dd < BD; ++dd) {
                const float* xp = &Xt[buf][dd * BM + 8 * ty];
                float4 xa = *(const float4*)(xp);
                float4 xb = *(const float4*)(xp + 4);
                const float* ep = &Et[buf][dd * BK + 4 * tx];
                float4 e0 = *(const float4*)(ep);
                float4 e1 = *(const float4*)(ep + 128);
                float4 e2 = *(const float4*)(ep + 256);
                float4 e3 = *(const float4*)(ep + 384);
                float xv[8]  = {xa.x, xa.y, xa.z, xa.w, xb.x, xb.y, xb.z, xb.w};
                float ev[16] = {e0.x, e0.y, e0.z, e0.w, e1.x, e1.y, e1.z, e1.w,
                                e2.x, e2.y, e2.z, e2.w, e3.x, e3.y, e3.z, e3.w};
                #pragma unroll
                for (int i = 0; i < 8; ++i)
                    #pragma unroll
                    for (int j = 0; j < 16; ++j)
                        acc[i][j] = __fmaf_rn(xv[i], ev[j], acc[i][j]);
            }

            // store next tile into the other buffer (safe: its readers passed
            // the barrier at the top of this iteration)
            if (dc < DCS - 1) {
                const int nb = buf ^ 1;
                Et[nb][0 * BK + c0] = pe0.x; Et[nb][1 * BK + c0] = pe0.y;
                Et[nb][2 * BK + c0] = pe0.z; Et[nb][3 * BK + c0] = pe0.w;
                Et[nb][4 * BK + c0] = pe1.x; Et[nb][5 * BK + c0] = pe1.y;
                Et[nb][6 * BK + c0] = pe1.z; Et[nb][7 * BK + c0] = pe1.w;
                Et[nb][0 * BK + c1] = pe2.x; Et[nb][1 * BK + c1] = pe2.y;
                Et[nb][2 * BK + c1] = pe2.z; Et[nb][3 * BK + c1] = pe2.w;
                Et[nb][4 * BK + c1] = pe3.x; Et[nb][5 * BK + c1] = pe3.y;
                Et[nb][6 * BK + c1] = pe3.z; Et[nb][7 * BK + c1] = pe3.w;
                if (tid < 128) {
                    int db = 4 * xpart;
                    Xt[nb][(db + 0) * BM + xr] = px.x;
                    Xt[nb][(db + 1) * BM + xr] = px.y;
                    Xt[nb][(db + 2) * BM + xr] = px.z;
                    Xt[nb][(db + 3) * BM + xr] = px.w;
                }
            }
        }

        // ref fp32 score: s = fl(xx - 2*dot); strict < keeps lowest code in bin
        #pragma unroll
        for (int i = 0; i < 8; ++i) {
            #pragma unroll
            for (int j = 0; j < 4; ++j) {
                #pragma unroll
                for (int l = 0; l < 4; ++l) {
                    float s = __fmaf_rn(-2.0f, acc[i][4 * j + l], xrow[i]);
                    int code = k0 + 128 * j + 4 * tx + l;
                    if (s < bestv[i]) { bestv[i] = s; besti[i] = code; }
                }
            }
        }
    }

    // ---- cross-thread argmin reduction (reuse Et[0]: 8KB vals + 8KB idx) ----
    __syncthreads();
    float* redv = &Et[0][0];                 // [64][32]
    int*   redi = (int*)&Et[0][2048];        // [64][32]
    #pragma unroll
    for (int i = 0; i < 8; ++i) {
        int row = 8 * ty + i;
        redv[row * 32 + tx] = bestv[i];
        redi[row * 32 + tx] = besti[i];
    }
    __syncthreads();
    if (tid < BM) {
        int row = tid;
        float v  = redv[row * 32];
        int  idx = redi[row * 32];
        for (int t = 1; t < 32; ++t) {
            float vv = redv[row * 32 + t];
            int   ii = redi[row * 32 + t];
            if (vv < v || (vv == v && ii < idx)) { v = vv; idx = ii; }
        }
        idxRow[row] = idx;
        out[OUT_IDX + r0 + row] = (float)idx;
        atomicMax(ws_maxidx, idx);
    }
    __syncthreads();

    // ---- gather quantized, straight-through output, loss partial ----
    double lsum = 0.0;
    for (int i = tid; i < BM * DQV; i += THREADS) {
        int row = i >> 7, dq = i & 127;
        int ki  = idxRow[row];
        float4 q  = emb4[(size_t)ki * DQV + dq];
        float4 xv = x4[(size_t)(r0 + row) * DQV + dq];
        float d0 = q.x - xv.x, d1 = q.y - xv.y, d2 = q.z - xv.z, d3 = q.w - xv.w;
        lsum += (double)d0 * (double)d0 + (double)d1 * (double)d1
              + (double)d2 * (double)d2 + (double)d3 * (double)d3;
        float4 o;
        o.x = xv.x + d0; o.y = xv.y + d1; o.z = xv.z + d2; o.w = xv.w + d3;
        out4[(size_t)(r0 + row) * DQV + dq] = o;
    }
    #pragma unroll
    for (int off = 32; off > 0; off >>= 1) lsum += __shfl_down(lsum, off);
    if ((tid & 63) == 0) atomicAdd(ws_loss, lsum);
}

__global__ void vq_final(const double* __restrict__ ws_loss,
                         const int* __restrict__ ws_maxidx,
                         float* __restrict__ out) {
    if (threadIdx.x == 0) {
        double mean = *ws_loss / (double)((size_t)N_ROWS * DIM);
        out[OUT_LOSS] = (float)(1.25 * mean);   // q_latent + 0.25*e_latent
        double L   = (double)(*ws_maxidx + 1);
        double avg = 1.0 / L;
        out[OUT_PERP] = (float)exp(-avg * log(avg + 1e-10));
    }
}

extern "C" void kernel_launch(void* const* d_in, const int* in_sizes, int n_in,
                              void* d_out, int out_size, void* d_ws, size_t ws_size,
                              hipStream_t stream) {
    const float* x   = (const float*)d_in[0];
    const float* emb = (const float*)d_in[1];
    float* out = (float*)d_out;

    float*  xx        = (float*)d_ws;                       // 16384 floats
    double* ws_loss   = (double*)((char*)d_ws + 65536);
    int*    ws_maxidx = (int*)((char*)d_ws + 65544);

    hipLaunchKernelGGL(init_ws, dim3(1), dim3(1), 0, stream, ws_loss, ws_maxidx);
    hipLaunchKernelGGL(xx_kernel, dim3(N_ROWS / 256), dim3(256), 0, stream,
                       (const float4*)x, xx);
    hipLaunchKernelGGL(vq_main, dim3(N_ROWS / BM), dim3(THREADS), 0, stream,
                       x, emb, xx, out, ws_loss, ws_maxidx);
    hipLaunchKernelGGL(vq_final, dim3(1), dim3(64), 0, stream,
                       ws_loss, ws_maxidx, out);
}

// Round 4
// 2628.120 us; speedup vs baseline: 6.1544x; 6.1544x over previous
//
#include <hip/hip_runtime.h>
#include <math.h>

#define N_ROWS   16384
#define DIM      512
#define DQV      128          // DIM/4 float4s per row
#define K_CODES  8192
#define NSPLIT   2            // code-range split (occupancy: grid 512 = 2 blocks/CU)
#define KHALF    (K_CODES / NSPLIT)
#define BM       64           // rows per block
#define BK       512          // codes per strip
#define BD       8            // d-chunk per tile
#define DCS      (DIM / BD)   // 64 d-chunks
#define NSTRIP   (KHALF / BK) // 8 strips per half
#define THREADS  256

#define OUT_LOSS 8388608
#define OUT_PERP 8388609
#define OUT_IDX  8388610

// workspace layout (bytes)
#define WS_XX    0            // 16384 f32
#define WS_BV0   65536        // 16384 f32
#define WS_BI0   131072       // 16384 i32
#define WS_BV1   196608       // 16384 f32
#define WS_BI1   262144       // 16384 i32
#define WS_LOSS  327680       // double
#define WS_MAXI  327688       // int

__global__ void init_ws(double* ws_loss, int* ws_maxidx) {
    *ws_loss = 0.0;
    *ws_maxidx = 0;
}

// ---- numpy pairwise-sum emulation of xx[n] = np.sum(flat**2, axis=1) ----
__device__ __forceinline__ float p128_sq(const float4* p) {
    float4 q0 = p[0], q1 = p[1];
    float r0 = __fmul_rn(q0.x, q0.x), r1 = __fmul_rn(q0.y, q0.y);
    float r2 = __fmul_rn(q0.z, q0.z), r3 = __fmul_rn(q0.w, q0.w);
    float r4 = __fmul_rn(q1.x, q1.x), r5 = __fmul_rn(q1.y, q1.y);
    float r6 = __fmul_rn(q1.z, q1.z), r7 = __fmul_rn(q1.w, q1.w);
    #pragma unroll
    for (int t = 1; t < 16; ++t) {
        q0 = p[2 * t]; q1 = p[2 * t + 1];
        r0 = __fadd_rn(r0, __fmul_rn(q0.x, q0.x));
        r1 = __fadd_rn(r1, __fmul_rn(q0.y, q0.y));
        r2 = __fadd_rn(r2, __fmul_rn(q0.z, q0.z));
        r3 = __fadd_rn(r3, __fmul_rn(q0.w, q0.w));
        r4 = __fadd_rn(r4, __fmul_rn(q1.x, q1.x));
        r5 = __fadd_rn(r5, __fmul_rn(q1.y, q1.y));
        r6 = __fadd_rn(r6, __fmul_rn(q1.z, q1.z));
        r7 = __fadd_rn(r7, __fmul_rn(q1.w, q1.w));
    }
    return __fadd_rn(__fadd_rn(__fadd_rn(r0, r1), __fadd_rn(r2, r3)),
                     __fadd_rn(__fadd_rn(r4, r5), __fadd_rn(r6, r7)));
}

__global__ __launch_bounds__(256) void xx_kernel(const float4* __restrict__ x4,
                                                 float* __restrict__ xx) {
    int row = blockIdx.x * 256 + threadIdx.x;
    const float4* p = x4 + (size_t)row * DQV;
    float a = p128_sq(p);
    float b = p128_sq(p + 32);
    float c = p128_sq(p + 64);
    float d = p128_sq(p + 96);
    xx[row] = __fadd_rn(__fadd_rn(a, b), __fadd_rn(c, d));
}

// NOTE: plain __launch_bounds__(THREADS). Round-3's ",2" min-waves arg capped
// VGPR at 128 -> ~70 regs spilled -> 39 GB scratch writes. Body needs ~210.
__global__ __launch_bounds__(THREADS) void vq_main(const float* __restrict__ x,
                                                   const float* __restrict__ emb,
                                                   const float* __restrict__ xx,
                                                   float* __restrict__ bestval,
                                                   int* __restrict__ bestidx,
                                                   float* __restrict__ bestval1,
                                                   int* __restrict__ bestidx1) {
    // LDS: 2*16KB (Et) + 2*2KB (Xt) = ~36.9 KB
    __shared__ float Et[2][BD * BK];   // E tile [dd][code], double-buffered
    __shared__ float Xt[2][BD * BM];   // X tile [dd][row], double-buffered

    const int tid = threadIdx.x;
    const int tx  = tid & 31;             // code group
    const int ty  = tid >> 5;             // row group 0..7
    const int rt  = blockIdx.x >> 1;      // row tile
    const int h   = blockIdx.x & 1;       // code half
    const int r0  = rt * BM;
    const int kb  = h * KHALF;

    const float4* x4   = (const float4*)x;
    const float4* emb4 = (const float4*)emb;

    const int c0 = tid;        // staging code ids within strip
    const int c1 = tid + 256;
    const int xr    = tid >> 1;           // staging row (tid<128)
    const int xpart = tid & 1;            // which float4 of the d-chunk

    // per-thread row norms (ref: s = fl(xx - 2*dot); ee vanishes in fp32 ulp(xx))
    float xrow[8];
    #pragma unroll
    for (int i = 0; i < 8; ++i) xrow[i] = xx[r0 + 8 * ty + i];

    float bestv[8];
    int   besti[8];
    #pragma unroll
    for (int i = 0; i < 8; ++i) { bestv[i] = 3.402823466e38f; besti[i] = 0; }

    float4 pe0, pe1, pe2, pe3, px;

    // prefetch (strip 0, dc 0)
    pe0 = emb4[(size_t)(kb + c0) * DQV + 0];
    pe1 = emb4[(size_t)(kb + c0) * DQV + 1];
    pe2 = emb4[(size_t)(kb + c1) * DQV + 0];
    pe3 = emb4[(size_t)(kb + c1) * DQV + 1];
    if (tid < 128) px = x4[(size_t)(r0 + xr) * DQV + xpart];

    for (int kc = 0; kc < NSTRIP; ++kc) {
        const int k0 = kb + kc * BK;

        float acc[8][16];
        #pragma unroll
        for (int i = 0; i < 8; ++i)
            #pragma unroll
            for (int j = 0; j < 16; ++j) acc[i][j] = 0.0f;

        __syncthreads();   // prior strip finished all reads of buf0
        {
            Et[0][0 * BK + c0] = pe0.x; Et[0][1 * BK + c0] = pe0.y;
            Et[0][2 * BK + c0] = pe0.z; Et[0][3 * BK + c0] = pe0.w;
            Et[0][4 * BK + c0] = pe1.x; Et[0][5 * BK + c0] = pe1.y;
            Et[0][6 * BK + c0] = pe1.z; Et[0][7 * BK + c0] = pe1.w;
            Et[0][0 * BK + c1] = pe2.x; Et[0][1 * BK + c1] = pe2.y;
            Et[0][2 * BK + c1] = pe2.z; Et[0][3 * BK + c1] = pe2.w;
            Et[0][4 * BK + c1] = pe3.x; Et[0][5 * BK + c1] = pe3.y;
            Et[0][6 * BK + c1] = pe3.z; Et[0][7 * BK + c1] = pe3.w;
            if (tid < 128) {
                int db = 4 * xpart;
                Xt[0][(db + 0) * BM + xr] = px.x;
                Xt[0][(db + 1) * BM + xr] = px.y;
                Xt[0][(db + 2) * BM + xr] = px.z;
                Xt[0][(db + 3) * BM + xr] = px.w;
            }
        }

        for (int dc = 0; dc < DCS; ++dc) {
            const int buf = dc & 1;
            __syncthreads();   // buf ready; other buf's readers done

            // prefetch next tile (next dc, or next strip's dc=0)
            {
                int nk0, ndq;
                if (dc < DCS - 1) { nk0 = k0; ndq = 2 * (dc + 1); }
                else { nk0 = (kc < NSTRIP - 1) ? k0 + BK : kb; ndq = 0; }
                pe0 = emb4[(size_t)(nk0 + c0) * DQV + ndq];
                pe1 = emb4[(size_t)(nk0 + c0) * DQV + ndq + 1];
                pe2 = emb4[(size_t)(nk0 + c1) * DQV + ndq];
                pe3 = emb4[(size_t)(nk0 + c1) * DQV + ndq + 1];
                if (tid < 128) px = x4[(size_t)(r0 + xr) * DQV + ndq + xpart];
            }

            // k-sequential fp32 FMA chain per (row,code) — bit-matches BLAS GEBP
            #pragma unroll
            for (int dd = 0; dd < BD; ++dd) {
                const float* xp = &Xt[buf][dd * BM + 8 * ty];
                float4 xa = *(const float4*)(xp);
                float4 xb = *(const float4*)(xp + 4);
                const float* ep = &Et[buf][dd * BK + 4 * tx];
                float4 e0 = *(const float4*)(ep);
                float4 e1 = *(const float4*)(ep + 128);
                float4 e2 = *(const float4*)(ep + 256);
                float4 e3 = *(const float4*)(ep + 384);
                float xv[8]  = {xa.x, xa.y, xa.z, xa.w, xb.x, xb.y, xb.z, xb.w};
                float ev[16] = {e0.x, e0.y, e0.z, e0.w, e1.x, e1.y, e1.z, e1.w,
                                e2.x, e2.y, e2.z, e2.w, e3.x, e3.y, e3.z, e3.w};
                #pragma unroll
                for (int i = 0; i < 8; ++i)
                    #pragma unroll
                    for (int j = 0; j < 16; ++j)
                        acc[i][j] = __fmaf_rn(xv[i], ev[j], acc[i][j]);
            }

            // store next tile into the other buffer
            if (dc < DCS - 1) {
                const int nb = buf ^ 1;
                Et[nb][0 * BK + c0] = pe0.x; Et[nb][1 * BK + c0] = pe0.y;
                Et[nb][2 * BK + c0] = pe0.z; Et[nb][3 * BK + c0] = pe0.w;
                Et[nb][4 * BK + c0] = pe1.x; Et[nb][5 * BK + c0] = pe1.y;
                Et[nb][6 * BK + c0] = pe1.z; Et[nb][7 * BK + c0] = pe1.w;
                Et[nb][0 * BK + c1] = pe2.x; Et[nb][1 * BK + c1] = pe2.y;
                Et[nb][2 * BK + c1] = pe2.z; Et[nb][3 * BK + c1] = pe2.w;
                Et[nb][4 * BK + c1] = pe3.x; Et[nb][5 * BK + c1] = pe3.y;
                Et[nb][6 * BK + c1] = pe3.z; Et[nb][7 * BK + c1] = pe3.w;
                if (tid < 128) {
                    int db = 4 * xpart;
                    Xt[nb][(db + 0) * BM + xr] = px.x;
                    Xt[nb][(db + 1) * BM + xr] = px.y;
                    Xt[nb][(db + 2) * BM + xr] = px.z;
                    Xt[nb][(db + 3) * BM + xr] = px.w;
                }
            }
        }

        // ref fp32 score: s = fl(xx - 2*dot); strict < keeps lowest code in bin
        #pragma unroll
        for (int i = 0; i < 8; ++i) {
            #pragma unroll
            for (int j = 0; j < 4; ++j) {
                #pragma unroll
                for (int l = 0; l < 4; ++l) {
                    float s = __fmaf_rn(-2.0f, acc[i][4 * j + l], xrow[i]);
                    int code = k0 + 128 * j + 4 * tx + l;
                    if (s < bestv[i]) { bestv[i] = s; besti[i] = code; }
                }
            }
        }
    }

    // ---- cross-thread argmin reduction (reuse Et[0]: 8KB vals + 8KB idx) ----
    __syncthreads();
    float* redv = &Et[0][0];                 // [64][32]
    int*   redi = (int*)&Et[0][2048];        // [64][32]
    #pragma unroll
    for (int i = 0; i < 8; ++i) {
        int row = 8 * ty + i;
        redv[row * 32 + tx] = bestv[i];
        redi[row * 32 + tx] = besti[i];
    }
    __syncthreads();
    if (tid < BM) {
        int row = tid;
        float v  = redv[row * 32];
        int  idx = redi[row * 32];
        for (int t = 1; t < 32; ++t) {
            float vv = redv[row * 32 + t];
            int   ii = redi[row * 32 + t];
            if (vv < v || (vv == v && ii < idx)) { v = vv; idx = ii; }
        }
        if (h == 0) { bestval[r0 + row]  = v; bestidx[r0 + row]  = idx; }
        else        { bestval1[r0 + row] = v; bestidx1[r0 + row] = idx; }
    }
}

// merge halves + gather + straight-through + loss
__global__ __launch_bounds__(THREADS) void vq_epi(const float* __restrict__ x,
                                                  const float* __restrict__ emb,
                                                  const float* __restrict__ bv0,
                                                  const int* __restrict__ bi0,
                                                  const float* __restrict__ bv1,
                                                  const int* __restrict__ bi1,
                                                  float* __restrict__ out,
                                                  double* __restrict__ ws_loss,
                                                  int* __restrict__ ws_maxidx) {
    __shared__ int idxRow[BM];
    const int tid = threadIdx.x;
    const int r0  = blockIdx.x * BM;
    const float4* x4   = (const float4*)x;
    const float4* emb4 = (const float4*)emb;
    float4*       out4 = (float4*)out;

    if (tid < BM) {
        int row = r0 + tid;
        float v0 = bv0[row]; int i0 = bi0[row];
        float v1 = bv1[row]; int i1 = bi1[row];
        // half0 codes all < half1 codes: tie (v1==v0) keeps i0 = numpy first-min
        int idx = (v1 < v0) ? i1 : i0;
        idxRow[tid] = idx;
        out[OUT_IDX + row] = (float)idx;
        atomicMax(ws_maxidx, idx);
    }
    __syncthreads();

    double lsum = 0.0;
    for (int i = tid; i < BM * DQV; i += THREADS) {
        int row = i >> 7, dq = i & 127;
        int ki  = idxRow[row];
        float4 q  = emb4[(size_t)ki * DQV + dq];
        float4 xv = x4[(size_t)(r0 + row) * DQV + dq];
        float d0 = q.x - xv.x, d1 = q.y - xv.y, d2 = q.z - xv.z, d3 = q.w - xv.w;
        lsum += (double)d0 * (double)d0 + (double)d1 * (double)d1
              + (double)d2 * (double)d2 + (double)d3 * (double)d3;
        float4 o;
        o.x = xv.x + d0; o.y = xv.y + d1; o.z = xv.z + d2; o.w = xv.w + d3;
        out4[(size_t)(r0 + row) * DQV + dq] = o;
    }
    #pragma unroll
    for (int off = 32; off > 0; off >>= 1) lsum += __shfl_down(lsum, off);
    if ((tid & 63) == 0) atomicAdd(ws_loss, lsum);
}

__global__ void vq_final(const double* __restrict__ ws_loss,
                         const int* __restrict__ ws_maxidx,
                         float* __restrict__ out) {
    if (threadIdx.x == 0) {
        double mean = *ws_loss / (double)((size_t)N_ROWS * DIM);
        out[OUT_LOSS] = (float)(1.25 * mean);   // q_latent + 0.25*e_latent
        double L   = (double)(*ws_maxidx + 1);
        double avg = 1.0 / L;
        out[OUT_PERP] = (float)exp(-avg * log(avg + 1e-10));
    }
}

extern "C" void kernel_launch(void* const* d_in, const int* in_sizes, int n_in,
                              void* d_out, int out_size, void* d_ws, size_t ws_size,
                              hipStream_t stream) {
    const float* x   = (const float*)d_in[0];
    const float* emb = (const float*)d_in[1];
    float* out = (float*)d_out;

    char* ws = (char*)d_ws;
    float*  xx        = (float*)(ws + WS_XX);
    float*  bv0       = (float*)(ws + WS_BV0);
    int*    bi0       = (int*)  (ws + WS_BI0);
    float*  bv1       = (float*)(ws + WS_BV1);
    int*    bi1       = (int*)  (ws + WS_BI1);
    double* ws_loss   = (double*)(ws + WS_LOSS);
    int*    ws_maxidx = (int*)  (ws + WS_MAXI);

    hipLaunchKernelGGL(init_ws, dim3(1), dim3(1), 0, stream, ws_loss, ws_maxidx);
    hipLaunchKernelGGL(xx_kernel, dim3(N_ROWS / 256), dim3(256), 0, stream,
                       (const float4*)x, xx);
    hipLaunchKernelGGL(vq_main, dim3((N_ROWS / BM) * NSPLIT), dim3(THREADS), 0, stream,
                       x, emb, xx, bv0, bi0, bv1, bi1);
    hipLaunchKernelGGL(vq_epi, dim3(N_ROWS / BM), dim3(THREADS), 0, stream,
                       x, emb, bv0, bi0, bv1, bi1, out, ws_loss, ws_maxidx);
    hipLaunchKernelGGL(vq_final, dim3(1), dim3(64), 0, stream,
                       ws_loss, ws_maxidx, out);
}